// Round 2
// baseline (257.646 us; speedup 1.0000x reference)
//
#include <hip/hip_runtime.h>
#include <hip/hip_fp16.h>

#define B_ 4
#define T_ 4096
#define D_ 1024
#define P_ 64

typedef _Float16 h8 __attribute__((ext_vector_type(8)));
typedef _Float16 h4 __attribute__((ext_vector_type(4)));
typedef float f32x4 __attribute__((ext_vector_type(4)));

// ---------------- kernel 0: W (D x 192 fp32) -> Wt (192 x D f16, transposed)
__global__ __launch_bounds__(256) void wt_kernel(const float* __restrict__ W,
                                                 _Float16* __restrict__ Wt) {
    int idx = blockIdx.x * 256 + threadIdx.x;      // 192*1024 total, exact
    int n = idx >> 10, k = idx & 1023;
    Wt[idx] = (_Float16)W[k * 192 + n];
}

// ---------------- kernel 1: qkv projection, f16 MFMA, BM=64 BN=192 BK=32
__global__ __launch_bounds__(256) void proj_kernel(
    const float* __restrict__ x, const _Float16* __restrict__ Wt,
    const float* __restrict__ bias,
    _Float16* __restrict__ qh, _Float16* __restrict__ kh, _Float16* __restrict__ vh)
{
    __shared__ _Float16 As[64][40];    // [row][k] pad->stride 40 halfs (16B-aligned rows)
    __shared__ _Float16 Bs[192][40];   // [n][k]
    const int tid = threadIdx.x;
    const int w = tid >> 6, lane = tid & 63, quad = lane >> 4, l16 = lane & 15;
    const int row0 = blockIdx.x * 64;

    float bvals[12];
#pragma unroll
    for (int nt = 0; nt < 12; nt++) bvals[nt] = bias[nt * 16 + l16];

    f32x4 acc[12];
#pragma unroll
    for (int i = 0; i < 12; i++) acc[i] = (f32x4){0.f, 0.f, 0.f, 0.f};

    const int arow = tid >> 2, ac0 = (tid & 3) * 8;

    float4 xa, xb;
    h8 wreg[3];
    {   // preload chunk 0: B tile is 192 rows x 32 halfs = 6144 = 256 thr * 3 * h8
        const float* xp = x + (size_t)(row0 + arow) * D_ + ac0;
        xa = *(const float4*)xp; xb = *(const float4*)(xp + 4);
#pragma unroll
        for (int p = 0; p < 3; p++) {
            int f = tid + 256 * p; int n = f >> 2, c0 = (f & 3) * 8;
            wreg[p] = *(const h8*)(Wt + (size_t)n * D_ + c0);
        }
    }

    for (int kc = 0; kc < 32; kc++) {
        if (kc) __syncthreads();               // prev MFMA reads done before overwrite
        h8 av;
        av[0]=(_Float16)xa.x; av[1]=(_Float16)xa.y; av[2]=(_Float16)xa.z; av[3]=(_Float16)xa.w;
        av[4]=(_Float16)xb.x; av[5]=(_Float16)xb.y; av[6]=(_Float16)xb.z; av[7]=(_Float16)xb.w;
        *(h8*)&As[arow][ac0] = av;
#pragma unroll
        for (int p = 0; p < 3; p++) {
            int f = tid + 256 * p; int n = f >> 2, c0 = (f & 3) * 8;
            *(h8*)&Bs[n][c0] = wreg[p];
        }
        if (kc + 1 < 32) {                     // register prefetch of next chunk
            int k0 = (kc + 1) * 32;
            const float* xp = x + (size_t)(row0 + arow) * D_ + k0 + ac0;
            xa = *(const float4*)xp; xb = *(const float4*)(xp + 4);
#pragma unroll
            for (int p = 0; p < 3; p++) {
                int f = tid + 256 * p; int n = f >> 2, c0 = (f & 3) * 8;
                wreg[p] = *(const h8*)(Wt + (size_t)n * D_ + k0 + c0);
            }
        }
        __syncthreads();
        h8 afrag = *(const h8*)&As[16 * w + l16][quad * 8];
#pragma unroll
        for (int nt = 0; nt < 12; nt++) {
            h8 bfrag = *(const h8*)&Bs[nt * 16 + l16][quad * 8];
            acc[nt] = __builtin_amdgcn_mfma_f32_16x16x32_f16(afrag, bfrag, acc[nt], 0, 0, 0);
        }
    }

    // epilogue: D[row=quad*4+reg][col=l16] per 16x16 tile; scatter to q/k/v (f16)
#pragma unroll
    for (int nt = 0; nt < 12; nt++) {
        int n = nt * 16 + l16;
        int g = n >> 6, p = n & 63;
        _Float16* dst = (g == 0) ? qh : (g == 1) ? kh : vh;
#pragma unroll
        for (int reg = 0; reg < 4; reg++) {
            int trow = row0 + 16 * w + quad * 4 + reg;
            dst[(size_t)trow * 64 + p] = (_Float16)(acc[nt][reg] + bvals[nt]);
        }
    }
}

// ---------------- kernel 2: flash attention, f16 MFMA, 64-row Q tile per block
__global__ __launch_bounds__(256) void attn_kernel(
    const _Float16* __restrict__ qh, const _Float16* __restrict__ kh,
    const _Float16* __restrict__ vh, float* __restrict__ out)
{
    __shared__ _Float16 Vt[80][72];      // [p][c], rows 64..79: ones-column trick (row64=1)
    __shared__ _Float16 Ps[4][16][72];   // wave-private P strips [w][m][c]
    const int tid = threadIdx.x;
    const int w = tid >> 6, lane = tid & 63, quad = lane >> 4, l16 = lane & 15;
    const int qt = blockIdx.x, b = blockIdx.y;
    const size_t base = (size_t)b * T_ * 64;

    // ones-column init: Vt rows 64..79 (row 64 = 1.0 -> l accumulates in o[4])
#pragma unroll
    for (int i = 0; i < 4; i++) {
        int r = 64 + i * 4 + w;
        Vt[r][lane] = (r == 64) ? (_Float16)1.0f : (_Float16)0.0f;
    }

    // Q fragments (A-layout), direct from global, kept in regs all kernel
    h8 qf[2];
    {
        const _Float16* qp = qh + base + (size_t)(qt * 64 + 16 * w + l16) * 64 + quad * 8;
        qf[0] = *(const h8*)qp;
        qf[1] = *(const h8*)(qp + 32);
    }

    f32x4 o[5];
#pragma unroll
    for (int i = 0; i < 5; i++) o[i] = (f32x4){0.f, 0.f, 0.f, 0.f};
    float m[4];
#pragma unroll
    for (int r = 0; r < 4; r++) m[r] = -1e30f;

    // V staging: thread loads rows vc0..vc0+3, cols vp0..vp0+3 (coalesced), reg-transpose
    const int vp0 = (tid & 15) * 4, vc0 = (tid >> 4) * 4;
    h4 vreg[4];
    {
        const _Float16* vp = vh + base + (size_t)vc0 * 64 + vp0;
#pragma unroll
        for (int i = 0; i < 4; i++) vreg[i] = *(const h4*)(vp + (size_t)i * 64);
    }

    for (int kt = 0; kt <= qt; kt++) {
        // K fragments (B-layout), direct from global (L2-resident), issued early
        h8 kf[4][2];
        {
            const _Float16* kp = kh + base + (size_t)(kt * 64 + l16) * 64 + quad * 8;
#pragma unroll
            for (int nt = 0; nt < 4; nt++) {
                kf[nt][0] = *(const h8*)(kp + (size_t)nt * 16 * 64);
                kf[nt][1] = *(const h8*)(kp + (size_t)nt * 16 * 64 + 32);
            }
        }
        // transpose V 4x4 in regs -> Vt[p][c]
#pragma unroll
        for (int j = 0; j < 4; j++) {
            h4 t;
            t[0] = vreg[0][j]; t[1] = vreg[1][j]; t[2] = vreg[2][j]; t[3] = vreg[3][j];
            *(h4*)&Vt[vp0 + j][vc0] = t;
        }
        if (kt < qt) {  // prefetch next V tile into regs
            const _Float16* vp = vh + base + (size_t)((kt + 1) * 64 + vc0) * 64 + vp0;
#pragma unroll
            for (int i = 0; i < 4; i++) vreg[i] = *(const h4*)(vp + (size_t)i * 64);
        }
        __syncthreads();

        // S = Q K^T  (wave strip: rows 16w..16w+15, all 64 cols)
        f32x4 s[4];
#pragma unroll
        for (int nt = 0; nt < 4; nt++) {
            f32x4 c = (f32x4){0.f, 0.f, 0.f, 0.f};
            c = __builtin_amdgcn_mfma_f32_16x16x32_f16(qf[0], kf[nt][0], c, 0, 0, 0);
            c = __builtin_amdgcn_mfma_f32_16x16x32_f16(qf[1], kf[nt][1], c, 0, 0, 0);
            s[nt] = c;
        }

        if (kt == qt) {  // causal mask on the diagonal tile
#pragma unroll
            for (int nt = 0; nt < 4; nt++)
#pragma unroll
                for (int reg = 0; reg < 4; reg++) {
                    int col = nt * 16 + l16, row = 16 * w + quad * 4 + reg;
                    if (col > row) s[nt][reg] = -1e30f;
                }
        }

        // online softmax: per-row running max (16-lane shfl max), l rides ones-column
        float pexp[4][4];
#pragma unroll
        for (int reg = 0; reg < 4; reg++) {
            float mx = fmaxf(fmaxf(s[0][reg], s[1][reg]), fmaxf(s[2][reg], s[3][reg]));
            mx = fmaxf(mx, __shfl_xor(mx, 1));
            mx = fmaxf(mx, __shfl_xor(mx, 2));
            mx = fmaxf(mx, __shfl_xor(mx, 4));
            mx = fmaxf(mx, __shfl_xor(mx, 8));
            float mnew = fmaxf(m[reg], mx);
            float alpha = __expf(m[reg] - mnew);
            m[reg] = mnew;
#pragma unroll
            for (int nt = 0; nt < 4; nt++) pexp[nt][reg] = __expf(s[nt][reg] - mnew);
#pragma unroll
            for (int nt = 0; nt < 5; nt++) o[nt][reg] *= alpha;
        }

        // P -> wave-private LDS strip (f16), no barrier needed (same-wave in-order DS)
#pragma unroll
        for (int nt = 0; nt < 4; nt++)
#pragma unroll
            for (int reg = 0; reg < 4; reg++)
                Ps[w][quad * 4 + reg][nt * 16 + l16] = (_Float16)pexp[nt][reg];

        // O += P V  (nt=4 tile accumulates row-sum l via ones column)
#pragma unroll
        for (int kc = 0; kc < 2; kc++) {
            h8 pa = *(const h8*)&Ps[w][l16][kc * 32 + quad * 8];
#pragma unroll
            for (int nt = 0; nt < 5; nt++) {
                h8 vb = *(const h8*)&Vt[nt * 16 + l16][kc * 32 + quad * 8];
                o[nt] = __builtin_amdgcn_mfma_f32_16x16x32_f16(pa, vb, o[nt], 0, 0, 0);
            }
        }
        __syncthreads();   // before next V overwrite
    }

    // l lives in col 64 == (nt=4, l16==0); broadcast from lane quad*16
    float linv[4];
#pragma unroll
    for (int reg = 0; reg < 4; reg++) {
        float lv = __shfl(o[4][reg], quad << 4);
        linv[reg] = 1.0f / lv;
    }
#pragma unroll
    for (int nt = 0; nt < 4; nt++)
#pragma unroll
        for (int reg = 0; reg < 4; reg++) {
            int trow = qt * 64 + 16 * w + quad * 4 + reg;
            out[base + (size_t)trow * 64 + nt * 16 + l16] = o[nt][reg] * linv[reg];
        }
}

extern "C" void kernel_launch(void* const* d_in, const int* in_sizes, int n_in,
                              void* d_out, int out_size, void* d_ws, size_t ws_size,
                              hipStream_t stream) {
    const float* x    = (const float*)d_in[0];
    const float* W    = (const float*)d_in[1];
    const float* bias = (const float*)d_in[2];
    float* out = (float*)d_out;
    char* ws = (char*)d_ws;
    // ws layout: q (2MB) | k (2MB) | v (2MB) | Wt (384KB)  => needs ~6.4MB
    _Float16* qh = (_Float16*)(ws);
    _Float16* kh = (_Float16*)(ws + (size_t)2 * 1024 * 1024);
    _Float16* vh = (_Float16*)(ws + (size_t)4 * 1024 * 1024);
    _Float16* Wt = (_Float16*)(ws + (size_t)6 * 1024 * 1024);

    wt_kernel<<<768, 256, 0, stream>>>(W, Wt);                       // 192*1024 elems
    proj_kernel<<<256, 256, 0, stream>>>(x, Wt, bias, qh, kh, vh);   // 16384/64 M-blocks
    attn_kernel<<<dim3(64, 4), 256, 0, stream>>>(qh, kh, vh, out);   // qt x batch
}

// Round 3
// 175.746 us; speedup vs baseline: 1.4660x; 1.4660x over previous
//
#include <hip/hip_runtime.h>
#include <hip/hip_fp16.h>

#define B_ 4
#define T_ 4096
#define D_ 1024
#define P_ 64

typedef _Float16 h8 __attribute__((ext_vector_type(8)));
typedef _Float16 h4 __attribute__((ext_vector_type(4)));
typedef float f32x4 __attribute__((ext_vector_type(4)));

// ---------------- kernel 0: W (D x 192 fp32) -> Wt (192 x D f16, transposed)
__global__ __launch_bounds__(256) void wt_kernel(const float* __restrict__ W,
                                                 _Float16* __restrict__ Wt) {
    int idx = blockIdx.x * 256 + threadIdx.x;      // 192*1024 total, exact
    int n = idx >> 10, k = idx & 1023;
    Wt[idx] = (_Float16)W[k * 192 + n];
}

// ---------------- kernel 1: qkv projection, f16 MFMA, BM=32 BN=192 BK=64, dbuf LDS
// grid 512 (2 blocks/CU, 8 waves/CU), 1 barrier per K-chunk, 16 chunks
__global__ __launch_bounds__(256) void proj_kernel(
    const float* __restrict__ x, const _Float16* __restrict__ Wt,
    const float* __restrict__ bias,
    _Float16* __restrict__ qh, _Float16* __restrict__ kh, _Float16* __restrict__ vh)
{
    __shared__ _Float16 As[2][32][72];    // [buf][row][k] (BK=64 + 8 pad)
    __shared__ _Float16 Bs[2][192][72];   // [buf][n][k]
    const int tid = threadIdx.x;
    const int w = tid >> 6, lane = tid & 63, quad = lane >> 4, l16 = lane & 15;
    const int row0 = blockIdx.x * 32;
    const int mstrip = w & 1;         // 16-row strip within the 32-row tile
    const int nbase = (w >> 1) * 6;   // 6 of 12 N-tiles per wave

    float bvals[6];
#pragma unroll
    for (int nt = 0; nt < 6; nt++) bvals[nt] = bias[(nbase + nt) * 16 + l16];

    f32x4 acc[6];
#pragma unroll
    for (int i = 0; i < 6; i++) acc[i] = (f32x4){0.f, 0.f, 0.f, 0.f};

    // A staging: 32x64 halfs = 2048 = 256 thr * h8
    const int arow = tid >> 3, ac0 = (tid & 7) * 8;

    float4 xa, xb;
    h8 wreg[6];   // B staging: 192x64 = 12288 = 256 * 6 * h8
    {
        const float* xp = x + (size_t)(row0 + arow) * D_ + ac0;
        xa = *(const float4*)xp; xb = *(const float4*)(xp + 4);
#pragma unroll
        for (int p = 0; p < 6; p++) {
            int f = tid + 256 * p; int n = f >> 3, c0 = (f & 7) * 8;
            wreg[p] = *(const h8*)(Wt + (size_t)n * D_ + c0);
        }
    }

    for (int kc = 0; kc < 16; kc++) {
        const int buf = kc & 1;
        h8 av;
        av[0]=(_Float16)xa.x; av[1]=(_Float16)xa.y; av[2]=(_Float16)xa.z; av[3]=(_Float16)xa.w;
        av[4]=(_Float16)xb.x; av[5]=(_Float16)xb.y; av[6]=(_Float16)xb.z; av[7]=(_Float16)xb.w;
        *(h8*)&As[buf][arow][ac0] = av;
#pragma unroll
        for (int p = 0; p < 6; p++) {
            int f = tid + 256 * p; int n = f >> 3, c0 = (f & 7) * 8;
            *(h8*)&Bs[buf][n][c0] = wreg[p];
        }
        if (kc + 1 < 16) {                 // register prefetch of next chunk
            int k0 = (kc + 1) * 64;
            const float* xp = x + (size_t)(row0 + arow) * D_ + k0 + ac0;
            xa = *(const float4*)xp; xb = *(const float4*)(xp + 4);
#pragma unroll
            for (int p = 0; p < 6; p++) {
                int f = tid + 256 * p; int n = f >> 3, c0 = (f & 7) * 8;
                wreg[p] = *(const h8*)(Wt + (size_t)n * D_ + k0 + c0);
            }
        }
        __syncthreads();   // buf ready; prev buf's readers already past last barrier
        h8 a0 = *(const h8*)&As[buf][16 * mstrip + l16][quad * 8];
        h8 a1 = *(const h8*)&As[buf][16 * mstrip + l16][32 + quad * 8];
#pragma unroll
        for (int nt = 0; nt < 6; nt++) {
            h8 b0 = *(const h8*)&Bs[buf][(nbase + nt) * 16 + l16][quad * 8];
            h8 b1 = *(const h8*)&Bs[buf][(nbase + nt) * 16 + l16][32 + quad * 8];
            acc[nt] = __builtin_amdgcn_mfma_f32_16x16x32_f16(a0, b0, acc[nt], 0, 0, 0);
            acc[nt] = __builtin_amdgcn_mfma_f32_16x16x32_f16(a1, b1, acc[nt], 0, 0, 0);
        }
    }

    // epilogue: D[row=quad*4+reg][col=l16]; scatter to q/k/v (f16)
#pragma unroll
    for (int nt = 0; nt < 6; nt++) {
        int n = (nbase + nt) * 16 + l16;
        int g = n >> 6, p = n & 63;
        _Float16* dst = (g == 0) ? qh : (g == 1) ? kh : vh;
#pragma unroll
        for (int reg = 0; reg < 4; reg++) {
            int trow = row0 + 16 * mstrip + quad * 4 + reg;
            dst[(size_t)trow * 64 + p] = (_Float16)(acc[nt][reg] + bvals[nt]);
        }
    }
}

// ---------------- kernel 2: flash attention chunks (split-K), f16 MFMA
// block = one chunk of C k-tiles for one (b, qt); writes partial O + (m,l), or
// final out when direct==1.
__global__ __launch_bounds__(256) void attn_kernel(
    const _Float16* __restrict__ qh, const _Float16* __restrict__ kh,
    const _Float16* __restrict__ vh, float* __restrict__ out,
    float* __restrict__ Opart, float2* __restrict__ ml,
    int lgC, int NC1, int direct)
{
    __shared__ _Float16 Vt[2][80][72];   // dbuf; rows 64..79: ones-column (row64=1)
    __shared__ _Float16 Ps[4][16][72];   // wave-private P strips
    const int tid = threadIdx.x;
    const int w = tid >> 6, lane = tid & 63, quad = lane >> 4, l16 = lane & 15;
    const int C = 1 << lgC;

    // chunk id -> (b, qt, k0, cnt)  (all scalar/uniform)
    const int cid = blockIdx.x;
    const int b = cid / NC1;
    int rem = cid - b * NC1;
    int qt = 0, k0 = 0, cnt = 1;
    for (int q = 0; q < 64; q++) {
        int nc = (q + C) >> lgC;           // ceil((q+1)/C)
        if (rem < nc) { qt = q; k0 = rem << lgC; cnt = min(C, q + 1 - k0); break; }
        rem -= nc;
    }
    const size_t base = (size_t)b * T_ * 64;

    // ones-column init (both buffers)
#pragma unroll
    for (int buf = 0; buf < 2; buf++)
#pragma unroll
        for (int i = 0; i < 4; i++) {
            int r = 64 + i * 4 + w;
            Vt[buf][r][lane] = (r == 64) ? (_Float16)1.0f : (_Float16)0.0f;
        }

    // Q fragments (A-layout), direct from global, kept in regs
    h8 qf[2];
    {
        const _Float16* qp = qh + base + (size_t)(qt * 64 + 16 * w + l16) * 64 + quad * 8;
        qf[0] = *(const h8*)qp;
        qf[1] = *(const h8*)(qp + 32);
    }

    f32x4 o[5];
#pragma unroll
    for (int i = 0; i < 5; i++) o[i] = (f32x4){0.f, 0.f, 0.f, 0.f};
    float m[4];
#pragma unroll
    for (int r = 0; r < 4; r++) m[r] = -1e30f;

    // V staging regs (coalesced 4x4), transposed into Vt each iter
    const int vp0 = (tid & 15) * 4, vc0 = (tid >> 4) * 4;
    h4 vreg[4];
    {
        const _Float16* vp = vh + base + (size_t)(k0 * 64 + vc0) * 64 + vp0;
#pragma unroll
        for (int i = 0; i < 4; i++) vreg[i] = *(const h4*)(vp + (size_t)i * 64);
    }

    const int kend = k0 + cnt;
    for (int kt = k0; kt < kend; kt++) {
        const int bufi = kt & 1;
        // K fragments (B-layout) direct from global (L2-resident)
        h8 kf[4][2];
        {
            const _Float16* kp = kh + base + (size_t)(kt * 64 + l16) * 64 + quad * 8;
#pragma unroll
            for (int nt = 0; nt < 4; nt++) {
                kf[nt][0] = *(const h8*)(kp + (size_t)nt * 16 * 64);
                kf[nt][1] = *(const h8*)(kp + (size_t)nt * 16 * 64 + 32);
            }
        }
        // transpose V 4x4 in regs -> Vt[bufi][p][c]
#pragma unroll
        for (int j = 0; j < 4; j++) {
            h4 t;
            t[0] = vreg[0][j]; t[1] = vreg[1][j]; t[2] = vreg[2][j]; t[3] = vreg[3][j];
            *(h4*)&Vt[bufi][vp0 + j][vc0] = t;
        }
        if (kt + 1 < kend) {   // prefetch next V tile
            const _Float16* vp = vh + base + (size_t)((kt + 1) * 64 + vc0) * 64 + vp0;
#pragma unroll
            for (int i = 0; i < 4; i++) vreg[i] = *(const h4*)(vp + (size_t)i * 64);
        }
        __syncthreads();   // Vt[bufi] ready (next iter writes the other buffer)

        // S = Q K^T
        f32x4 s[4];
#pragma unroll
        for (int nt = 0; nt < 4; nt++) {
            f32x4 c = (f32x4){0.f, 0.f, 0.f, 0.f};
            c = __builtin_amdgcn_mfma_f32_16x16x32_f16(qf[0], kf[nt][0], c, 0, 0, 0);
            c = __builtin_amdgcn_mfma_f32_16x16x32_f16(qf[1], kf[nt][1], c, 0, 0, 0);
            s[nt] = c;
        }

        if (kt == qt) {  // causal mask on the diagonal tile
#pragma unroll
            for (int nt = 0; nt < 4; nt++)
#pragma unroll
                for (int reg = 0; reg < 4; reg++) {
                    int col = nt * 16 + l16, row = 16 * w + quad * 4 + reg;
                    if (col > row) s[nt][reg] = -1e30f;
                }
        }

        // online softmax; row-sum l rides the ones-column in o[4]
        float pexp[4][4];
#pragma unroll
        for (int reg = 0; reg < 4; reg++) {
            float mx = fmaxf(fmaxf(s[0][reg], s[1][reg]), fmaxf(s[2][reg], s[3][reg]));
            mx = fmaxf(mx, __shfl_xor(mx, 1));
            mx = fmaxf(mx, __shfl_xor(mx, 2));
            mx = fmaxf(mx, __shfl_xor(mx, 4));
            mx = fmaxf(mx, __shfl_xor(mx, 8));
            float mnew = fmaxf(m[reg], mx);
            float alpha = __expf(m[reg] - mnew);
            m[reg] = mnew;
#pragma unroll
            for (int nt = 0; nt < 4; nt++) pexp[nt][reg] = __expf(s[nt][reg] - mnew);
#pragma unroll
            for (int nt = 0; nt < 5; nt++) o[nt][reg] *= alpha;
        }

        // P -> wave-private LDS strip (same-wave DS is in-order; no barrier)
#pragma unroll
        for (int nt = 0; nt < 4; nt++)
#pragma unroll
            for (int reg = 0; reg < 4; reg++)
                Ps[w][quad * 4 + reg][nt * 16 + l16] = (_Float16)pexp[nt][reg];

        // O += P V  (nt=4 accumulates l via ones column)
#pragma unroll
        for (int kc = 0; kc < 2; kc++) {
            h8 pa = *(const h8*)&Ps[w][l16][kc * 32 + quad * 8];
#pragma unroll
            for (int nt = 0; nt < 5; nt++) {
                h8 vb = *(const h8*)&Vt[bufi][nt * 16 + l16][kc * 32 + quad * 8];
                o[nt] = __builtin_amdgcn_mfma_f32_16x16x32_f16(pa, vb, o[nt], 0, 0, 0);
            }
        }
    }

    if (direct) {
        float linv[4];
#pragma unroll
        for (int reg = 0; reg < 4; reg++) {
            float lv = __shfl(o[4][reg], quad << 4);
            linv[reg] = 1.0f / lv;
        }
#pragma unroll
        for (int nt = 0; nt < 4; nt++)
#pragma unroll
            for (int reg = 0; reg < 4; reg++) {
                int trow = qt * 64 + 16 * w + quad * 4 + reg;
                out[base + (size_t)trow * 64 + nt * 16 + l16] = o[nt][reg] * linv[reg];
            }
    } else {
        float* op = Opart + (size_t)cid * 4096;
#pragma unroll
        for (int nt = 0; nt < 4; nt++)
#pragma unroll
            for (int reg = 0; reg < 4; reg++)
                op[(16 * w + quad * 4 + reg) * 64 + nt * 16 + l16] = o[nt][reg];
        if (l16 == 0) {
#pragma unroll
            for (int reg = 0; reg < 4; reg++) {
                int r = 16 * w + quad * 4 + reg;
                ml[(size_t)cid * 64 + r] = make_float2(m[reg], o[4][reg]);  // o[4] col64 @ l16==0
            }
        }
    }
}

// ---------------- kernel 3: merge split-K partials (flash merge)
__global__ __launch_bounds__(256) void combine_kernel(
    const float* __restrict__ Opart, const float2* __restrict__ ml,
    float* __restrict__ out, int lgC, int NC1)
{
    const int C = 1 << lgC;
    const int task = blockIdx.x;            // b*64 + qt
    const int b = task >> 6, qt = task & 63;
    int pref = 0;
    for (int q = 0; q < qt; q++) pref += (q + C) >> lgC;
    const int cbase = b * NC1 + pref;
    const int nch = (qt + C) >> lgC;

    const int r = threadIdx.x >> 2;              // local row 0..63
    const int c0 = (threadIdx.x & 3) << 4;       // col base {0,16,32,48}

    float M = -1e30f;
    for (int i = 0; i < nch; i++) M = fmaxf(M, ml[(size_t)(cbase + i) * 64 + r].x);
    float L = 0.f, acc[16];
#pragma unroll
    for (int t = 0; t < 16; t++) acc[t] = 0.f;
    for (int i = 0; i < nch; i++) {
        float2 v = ml[(size_t)(cbase + i) * 64 + r];
        float sc = __expf(v.x - M);
        L += sc * v.y;
        const float* op = Opart + (size_t)(cbase + i) * 4096 + r * 64 + c0;
#pragma unroll
        for (int t = 0; t < 4; t++) {
            float4 x4 = *(const float4*)(op + 4 * t);
            acc[4*t+0] += sc * x4.x; acc[4*t+1] += sc * x4.y;
            acc[4*t+2] += sc * x4.z; acc[4*t+3] += sc * x4.w;
        }
    }
    float inv = 1.0f / L;
    float* po = out + ((size_t)b * T_ + qt * 64 + r) * 64 + c0;
#pragma unroll
    for (int t = 0; t < 4; t++) {
        float4 x4 = { acc[4*t]*inv, acc[4*t+1]*inv, acc[4*t+2]*inv, acc[4*t+3]*inv };
        *(float4*)(po + 4 * t) = x4;
    }
}

extern "C" void kernel_launch(void* const* d_in, const int* in_sizes, int n_in,
                              void* d_out, int out_size, void* d_ws, size_t ws_size,
                              hipStream_t stream) {
    const float* x    = (const float*)d_in[0];
    const float* W    = (const float*)d_in[1];
    const float* bias = (const float*)d_in[2];
    float* out = (float*)d_out;
    char* ws = (char*)d_ws;
    // ws: q(2MB) | k(2MB) | v(2MB) | Wt(.375MB) | @8MB: Opart | ml
    _Float16* qh = (_Float16*)(ws);
    _Float16* kh = (_Float16*)(ws + (size_t)2 * 1024 * 1024);
    _Float16* vh = (_Float16*)(ws + (size_t)4 * 1024 * 1024);
    _Float16* Wt = (_Float16*)(ws + (size_t)6 * 1024 * 1024);
    const size_t pbase = (size_t)8 * 1024 * 1024;

    // pick smallest chunk size C (max split) whose partials fit in ws
    int lgC = -1, nc1 = 64;
    for (int lg = 3; lg <= 6; lg++) {
        int C = 1 << lg, n1 = 0;
        for (int q = 0; q < 64; q++) n1 += (q + C) >> lg;
        size_t need = pbase + (size_t)4 * n1 * (4096 * 4 + 64 * 8);
        if (need <= ws_size) { lgC = lg; nc1 = n1; break; }
    }
    int direct = (lgC < 0) ? 1 : 0;
    if (direct) { lgC = 6; nc1 = 64; }
    float*  Opart = (float*)(ws + pbase);
    float2* mlp   = (float2*)(ws + pbase + (size_t)4 * nc1 * 4096 * 4);

    wt_kernel<<<768, 256, 0, stream>>>(W, Wt);
    proj_kernel<<<512, 256, 0, stream>>>(x, Wt, bias, qh, kh, vh);
    attn_kernel<<<4 * nc1, 256, 0, stream>>>(qh, kh, vh, out, Opart, mlp, lgC, nc1, direct);
    if (!direct)
        combine_kernel<<<256, 256, 0, stream>>>(Opart, mlp, out, lgC, nc1);
}